// Round 5
// baseline (1229.967 us; speedup 1.0000x reference)
//
#include <hip/hip_runtime.h>
#include <hip/hip_bf16.h>

typedef __bf16 bf16x8 __attribute__((ext_vector_type(8)));
typedef float f32x4 __attribute__((ext_vector_type(4)));

#define LSEQ 512
#define NB   256   // batch
#define NH   256   // hidden
#define KD   512   // NH + D (gate input g = [h, x])
#define HROW_U64 (NH / 2)            // u64 per h row (2 bf16 cols per u64)
#define HBUF_U64 (NB * HROW_U64)     // one parity buffer: 32768 u64 (256 KB)

// Re-inits both h buffers' parity-0 with tag-0 packed h0 every launch (ws is
// re-poisoned to 0xAA before each timed call; 0xAAAAAAAA never matches a tag
// < 513, so the parity-1 buffers need no init). End-of-kernel release flushes
// these stores to L3, so lstm_main's first polls see them on any XCD.
__global__ __launch_bounds__(256) void lstm_prep(const float* __restrict__ h0,
                                                 unsigned long long* __restrict__ hbufS,
                                                 unsigned long long* __restrict__ hbufF) {
  int g = blockIdx.x * 256 + threadIdx.x;   // grid 128 -> g in [0, 32768)
  unsigned pa = (unsigned)__builtin_bit_cast(unsigned short, (__bf16)h0[2 * g]);
  unsigned pb = (unsigned)__builtin_bit_cast(unsigned short, (__bf16)h0[2 * g + 1]);
  unsigned long long pkt = (unsigned long long)(pa | (pb << 16));  // tag 0
  hbufS[g] = pkt;
  hbufF[g] = pkt;
}

// Persistent LSTM. blockIdx.x = row-group r (16 batch rows), blockIdx.y =
// col-block cb (16 hidden cols of each of 4 gates). 256 blocks, 1/CU.
//
// Sync protocol: tagged 64-bit packets ((step)<<32 | bf16-pair); store IS
// the arrival, poll IS the data load; parity double-buffer is ABA-safe.
// DUAL-PATH exchange:
//   fast: sc0 stores/loads — stays in / reads the XCD-local L2 (~200 cy).
//         With dim3(16,16), linear id = r + 16*cb -> XCD = r%8 under
//         round-robin, so all 16 siblings share an XCD and the fast path
//         engages. Placement is a heuristic only.
//   slow: sc0 sc1 stores/loads — through memory-side L3, the guaranteed
//         coherence point (round-4's proven path). Poll alternates fast
//         then slow; tags only move forward so neither path can
//         false-positive; slow path guarantees progress on any placement.
__global__ __launch_bounds__(256) void lstm_main(
    const float* __restrict__ x,
    const float* __restrict__ c0,
    const float* __restrict__ Wf, const float* __restrict__ bf_,
    const float* __restrict__ Wi, const float* __restrict__ bi_,
    const float* __restrict__ Wc, const float* __restrict__ bc_,
    const float* __restrict__ Wo, const float* __restrict__ bo_,
    float* __restrict__ out,
    unsigned long long* __restrict__ hbufS,  // slow (L3) tagged h pairs
    unsigned long long* __restrict__ hbufF)  // fast (L2) tagged h pairs
{
  const int r    = blockIdx.x;   // row-group 0..15
  const int cb   = blockIdx.y;   // col-block 0..15
  const int tid  = threadIdx.x;
  const int w    = tid >> 6;     // wave id == gate id (f, i, c~, o)
  const int lane = tid & 63;
  const int l15  = lane & 15;
  const int kg   = lane >> 4;    // k-group 0..3 within MFMA fragment

  __shared__ __align__(16) unsigned char Ash[16 * KD * 2];  // 16 x 512 bf16, XOR-swizzled
  __shared__ float zbuf[4][16][17];                         // gate pre-activations

  const int j0    = cb * 16;
  const int brow0 = r * 16;

  // ---- B fragments: this wave's gate weights resident in VGPRs (64/lane) ----
  const float* Wg = (w == 0) ? Wf : (w == 1) ? Wi : (w == 2) ? Wc : Wo;
  bf16x8 bfrag[16];
  {
    const float* wp = Wg + (size_t)(j0 + l15) * KD + kg * 8;
#pragma unroll
    for (int s = 0; s < 16; ++s) {
      float4 lo = *(const float4*)(wp + s * 32);
      float4 hi = *(const float4*)(wp + s * 32 + 4);
      bf16x8 v;
      v[0] = (__bf16)lo.x; v[1] = (__bf16)lo.y; v[2] = (__bf16)lo.z; v[3] = (__bf16)lo.w;
      v[4] = (__bf16)hi.x; v[5] = (__bf16)hi.y; v[6] = (__bf16)hi.z; v[7] = (__bf16)hi.w;
      bfrag[s] = v;
    }
  }

  // ---- epilogue mapping: one thread per (row, col) of the 16x16 tile ----
  const int erow = tid >> 4, ecol = tid & 15;
  const int brow = brow0 + erow;
  const int jcol = j0 + ecol;
  const float biasf = bf_[jcol], biasi = bi_[jcol], biasc = bc_[jcol], biaso = bo_[jcol];
  float cst   = c0[brow * NH + jcol];
  float hlast = 0.f;

  const int swz  = (erow & 7) << 4;
  const int base = erow * 1024;

  // x_0 prefetch
  float4 xr0, xr1, xr2, xr3;
  {
    const float* xp = x + ((size_t)brow * 256 + ecol * 16);
    xr0 = ((const float4*)xp)[0]; xr1 = ((const float4*)xp)[1];
    xr2 = ((const float4*)xp)[2]; xr3 = ((const float4*)xp)[3];
  }

  for (int t = 0; t < LSEQ; ++t) {
    // 1) stage x_t (already in regs) into LDS k-region 256..511
    {
      bf16x8 p0, p1;
      p0[0] = (__bf16)xr0.x; p0[1] = (__bf16)xr0.y; p0[2] = (__bf16)xr0.z; p0[3] = (__bf16)xr0.w;
      p0[4] = (__bf16)xr1.x; p0[5] = (__bf16)xr1.y; p0[6] = (__bf16)xr1.z; p0[7] = (__bf16)xr1.w;
      p1[0] = (__bf16)xr2.x; p1[1] = (__bf16)xr2.y; p1[2] = (__bf16)xr2.z; p1[3] = (__bf16)xr2.w;
      p1[4] = (__bf16)xr3.x; p1[5] = (__bf16)xr3.y; p1[6] = (__bf16)xr3.z; p1[7] = (__bf16)xr3.w;
      *(uint4*)&Ash[(base + (256 + ecol * 16) * 2) ^ swz]     = __builtin_bit_cast(uint4, p0);
      *(uint4*)&Ash[(base + (256 + ecol * 16 + 8) * 2) ^ swz] = __builtin_bit_cast(uint4, p1);
    }
    // 2) issue x_{t+1} prefetch (hides under poll + MFMAs)
    {
      int tn = (t + 1 < LSEQ) ? t + 1 : t;
      const float* xp = x + ((size_t)tn * NB * 256 + (size_t)brow * 256 + ecol * 16);
      xr0 = ((const float4*)xp)[0]; xr1 = ((const float4*)xp)[1];
      xr2 = ((const float4*)xp)[2]; xr3 = ((const float4*)xp)[3];
    }
    __syncthreads();  // sync1: x staged

    // 3) x-half MFMAs (k = 256..511) — independent of h_t
    f32x4 acc = {0.f, 0.f, 0.f, 0.f};
#pragma unroll
    for (int s = 8; s < 16; ++s) {
      int ab = ((l15 * 1024) + (s * 32 + kg * 8) * 2) ^ ((l15 & 7) << 4);
      bf16x8 a = *(const bf16x8*)&Ash[ab];
      acc = __builtin_amdgcn_mfma_f32_16x16x32_bf16(a, bfrag[s], acc, 0, 0, 0);
    }

    // 4) poll h_t: thread owns row brow, u64 slots {i*16 + ecol}; fast (L2)
    //    check first, then slow (L3). Winning iteration's regs hold the data.
    unsigned long long hv[8];
    {
      const size_t roff = (size_t)(t & 1) * HBUF_U64 + (size_t)brow * HROW_U64 + ecol;
      const unsigned long long* hpF = hbufF + roff;
      const unsigned long long* hpS = hbufS + roff;
      const unsigned tu = (unsigned)t;
      while (1) {
        unsigned long long f0, f1, f2, f3, f4, f5, f6, f7;
        asm volatile(
            "global_load_dwordx2 %0, %8, off sc0\n\t"
            "global_load_dwordx2 %1, %8, off offset:128 sc0\n\t"
            "global_load_dwordx2 %2, %8, off offset:256 sc0\n\t"
            "global_load_dwordx2 %3, %8, off offset:384 sc0\n\t"
            "global_load_dwordx2 %4, %8, off offset:512 sc0\n\t"
            "global_load_dwordx2 %5, %8, off offset:640 sc0\n\t"
            "global_load_dwordx2 %6, %8, off offset:768 sc0\n\t"
            "global_load_dwordx2 %7, %8, off offset:896 sc0\n\t"
            "s_waitcnt vmcnt(0)"
            : "=&v"(f0), "=&v"(f1), "=&v"(f2), "=&v"(f3),
              "=&v"(f4), "=&v"(f5), "=&v"(f6), "=&v"(f7)
            : "v"(hpF)
            : "memory");
        bool ok = ((unsigned)(f0 >> 32) == tu) & ((unsigned)(f1 >> 32) == tu) &
                  ((unsigned)(f2 >> 32) == tu) & ((unsigned)(f3 >> 32) == tu) &
                  ((unsigned)(f4 >> 32) == tu) & ((unsigned)(f5 >> 32) == tu) &
                  ((unsigned)(f6 >> 32) == tu) & ((unsigned)(f7 >> 32) == tu);
        if (ok) {
          hv[0] = f0; hv[1] = f1; hv[2] = f2; hv[3] = f3;
          hv[4] = f4; hv[5] = f5; hv[6] = f6; hv[7] = f7;
          break;
        }
        asm volatile(
            "global_load_dwordx2 %0, %8, off sc0 sc1\n\t"
            "global_load_dwordx2 %1, %8, off offset:128 sc0 sc1\n\t"
            "global_load_dwordx2 %2, %8, off offset:256 sc0 sc1\n\t"
            "global_load_dwordx2 %3, %8, off offset:384 sc0 sc1\n\t"
            "global_load_dwordx2 %4, %8, off offset:512 sc0 sc1\n\t"
            "global_load_dwordx2 %5, %8, off offset:640 sc0 sc1\n\t"
            "global_load_dwordx2 %6, %8, off offset:768 sc0 sc1\n\t"
            "global_load_dwordx2 %7, %8, off offset:896 sc0 sc1\n\t"
            "s_waitcnt vmcnt(0)"
            : "=&v"(f0), "=&v"(f1), "=&v"(f2), "=&v"(f3),
              "=&v"(f4), "=&v"(f5), "=&v"(f6), "=&v"(f7)
            : "v"(hpS)
            : "memory");
        ok = ((unsigned)(f0 >> 32) == tu) & ((unsigned)(f1 >> 32) == tu) &
             ((unsigned)(f2 >> 32) == tu) & ((unsigned)(f3 >> 32) == tu) &
             ((unsigned)(f4 >> 32) == tu) & ((unsigned)(f5 >> 32) == tu) &
             ((unsigned)(f6 >> 32) == tu) & ((unsigned)(f7 >> 32) == tu);
        if (ok) {
          hv[0] = f0; hv[1] = f1; hv[2] = f2; hv[3] = f3;
          hv[4] = f4; hv[5] = f5; hv[6] = f6; hv[7] = f7;
          break;
        }
      }
    }

    // 5) stage h into LDS k-region 0..255 (low 32 bits = bf16 pair)
#pragma unroll
    for (int i = 0; i < 8; ++i)
      *(unsigned*)&Ash[(base + (i * 16 + ecol) * 4) ^ swz] = (unsigned)hv[i];
    __syncthreads();  // sync2: h staged

    // 6) h-half MFMAs (k = 0..255)
#pragma unroll
    for (int s = 0; s < 8; ++s) {
      int ab = ((l15 * 1024) + (s * 32 + kg * 8) * 2) ^ ((l15 & 7) << 4);
      bf16x8 a = *(const bf16x8*)&Ash[ab];
      acc = __builtin_amdgcn_mfma_f32_16x16x32_bf16(a, bfrag[s], acc, 0, 0, 0);
    }
    // C/D layout: col = lane&15, row = (lane>>4)*4 + reg  [m89-verified]
#pragma unroll
    for (int v4i = 0; v4i < 4; ++v4i) zbuf[w][kg * 4 + v4i][l15] = acc[v4i];
    __syncthreads();  // sync3: zbuf complete

    // 7) elementwise gate math; one thread per (row, col)
    float zf = zbuf[0][erow][ecol] + biasf;
    float zi = zbuf[1][erow][ecol] + biasi;
    float zc = zbuf[2][erow][ecol] + biasc;
    float zo = zbuf[3][erow][ecol] + biaso;
    float fg    = 1.f / (1.f + __expf(-zf));
    float ig    = 1.f / (1.f + __expf(-zi));
    float ccand = 1.f - 2.f / (__expf(2.f * zc) + 1.f);   // tanh
    float og    = 1.f / (1.f + __expf(-zo));
    cst   = fg * cst + ig * ccand;
    float tc = 1.f - 2.f / (__expf(2.f * cst) + 1.f);     // tanh
    hlast = og * tc;

    // 8) publish h_{t+1}: one tagged 64-bit packet per thread-pair, stored
    //    twice — fast (sc0 -> local L2) then slow (sc0 sc1 -> L3). Fire and
    //    forget; no drain, no counter.
    unsigned mybits = (unsigned)__builtin_bit_cast(unsigned short, (__bf16)hlast);
    unsigned nbbits = __shfl_down(mybits, 1);
    if ((ecol & 1) == 0) {
      unsigned long long pkt =
          ((unsigned long long)(unsigned)(t + 1) << 32) |
          (unsigned long long)(mybits | (nbbits << 16));
      const size_t poff = (size_t)((t + 1) & 1) * HBUF_U64 +
                          (size_t)brow * HROW_U64 + cb * 8 + (ecol >> 1);
      asm volatile("global_store_dwordx2 %0, %1, off sc0"
                   :: "v"(hbufF + poff), "v"(pkt) : "memory");
      asm volatile("global_store_dwordx2 %0, %1, off sc0 sc1"
                   :: "v"(hbufS + poff), "v"(pkt) : "memory");
    }

    // 9) hAll output (off critical path, plain cached store)
    out[(size_t)t * NB * NH + brow * NH + jcol] = hlast;
  }

  // finals: h_final, c_final
  out[(size_t)LSEQ * NB * NH + brow * NH + jcol]           = hlast;
  out[(size_t)LSEQ * NB * NH + NB * NH + brow * NH + jcol] = cst;
}

extern "C" void kernel_launch(void* const* d_in, const int* in_sizes, int n_in,
                              void* d_out, int out_size, void* d_ws, size_t ws_size,
                              hipStream_t stream) {
  const float* x  = (const float*)d_in[0];
  const float* h0 = (const float*)d_in[1];
  const float* c0 = (const float*)d_in[2];
  const float* Wf = (const float*)d_in[3];
  const float* bf = (const float*)d_in[4];
  const float* bi_dummy = nullptr; (void)bi_dummy;
  const float* Wi = (const float*)d_in[5];
  const float* bi = (const float*)d_in[6];
  const float* Wc = (const float*)d_in[7];
  const float* bc = (const float*)d_in[8];
  const float* Wo = (const float*)d_in[9];
  const float* bo = (const float*)d_in[10];
  float* out = (float*)d_out;

  unsigned long long* hbufS = (unsigned long long*)d_ws;              // 2 x 256 KB
  unsigned long long* hbufF = hbufS + 2 * HBUF_U64;                   // 2 x 256 KB

  lstm_prep<<<128, 256, 0, stream>>>(h0, hbufS, hbufF);
  lstm_main<<<dim3(16, 16), 256, 0, stream>>>(x, c0, Wf, bf, Wi, bi, Wc, bc,
                                              Wo, bo, out, hbufS, hbufF);
}